// Round 7
// baseline (346.905 us; speedup 1.0000x reference)
//
#include <hip/hip_runtime.h>
#include <math.h>

#define N_NODES 100000
#define N_EDGES 3200000
#define EPS_F 1e-6f

#define NSLICE  8
#define SLICE_N 12500                     // nodes per slice (8*12500 = 100000)
#define NCHUNK  64
#define CHUNK_E (N_EDGES / NCHUNK)        // 50000 exactly

// gather batching: J edges per thread, static trip count
#define GJ      16
#define G_EPB   (256 * GJ)                // 4096 edges per block

// repack batching
#define RJ      8
#define R_EPB   (256 * RJ)                // 2048 edges per block

// ws layout (float indices):
//   [1..4]   : sum(p0), sum(p1), sum(p0^2), sum(p1^2)
//   [5]      : sum(node_sum^2)
//   CUR_OFF  : cur[N_EDGES]                       (12.8 MB)
//   SD_OFF   : packed int2 (src,dst)[N_EDGES]     (25.6 MB)
//   PART_OFF : partials[NCHUNK][N_NODES]          (25.6 MB)
//   V_OFF    : packed v[N_NODES]                  (0.4 MB)
#define CUR_OFF   64
#define SD_OFF    (CUR_OFF + N_EDGES)
#define PART_OFF  (SD_OFF + 2 * N_EDGES)
#define V_OFF     (PART_OFF + NCHUNK * N_NODES)
#define WS_FLOATS (V_OFF + N_NODES)

__device__ __forceinline__ float wave_reduce(float v) {
    #pragma unroll
    for (int off = 32; off > 0; off >>= 1) v += __shfl_down(v, off, 64);
    return v;
}

__device__ __forceinline__ void fadd_agent(float* p, float v) {
    unsafeAtomicAdd(p, v);   // only scalar-acc updates
}

// ---------------- pass 0: pack v = nf[:,0] into a dense 400 KB table ----------------
__global__ __launch_bounds__(256) void packv_kernel(
    const float* __restrict__ nf, float* __restrict__ ws)
{
    const int i = blockIdx.x * blockDim.x + threadIdx.x;
    if (i < N_NODES) ws[V_OFF + i] = nf[i * 4];
}

// ---------------- pass 1: repack edge_index (int32 or int64) -> int2 sd[] ----------------
__global__ __launch_bounds__(256) void repack_kernel(
    const void* __restrict__ eidx, float* __restrict__ ws)
{
    const int*       i32 = (const int*)eidx;
    const long long* i64 = (const long long*)eidx;

    // int64 values < 2^31 have zero hi-words at every odd int32 slot;
    // int32 has random node ids there (16 zeros ~ impossible).
    int any = 0;
    #pragma unroll
    for (int k = 1; k < 32; k += 2) any |= i32[k];
    const bool is32 = (any != 0);

    int2* sd = (int2*)(ws + SD_OFF);
    const int e_base = blockIdx.x * R_EPB + threadIdx.x;

    if (is32) {
        #pragma unroll
        for (int j = 0; j < RJ; ++j) {
            const int e = e_base + j * 256;
            if (e < N_EDGES) sd[e] = make_int2(i32[e], i32[N_EDGES + e]);
        }
    } else {
        #pragma unroll
        for (int j = 0; j < RJ; ++j) {
            const int e = e_base + j * 256;
            if (e < N_EDGES) sd[e] = make_int2((int)i64[e], (int)i64[N_EDGES + e]);
        }
    }
}

// ---------------- pass 2: gather + per-edge compute, forced-ILP ----------------
__global__ __launch_bounds__(256)
__attribute__((amdgpu_waves_per_eu(2, 2)))
void gather_kernel(
    const float*  __restrict__ logits,
    const float2* __restrict__ params,
    float*        __restrict__ ws)
{
    const float* vtab    = ws + V_OFF;
    const int2*  sd      = (const int2*)(ws + SD_OFF);
    float*       cur_out = ws + CUR_OFF;
    float*       acc     = ws + 1;

    const int e_base = blockIdx.x * G_EPB + threadIdx.x;

    int2  sdv[GJ];
    float vsv[GJ], vdv[GJ], lgv[GJ];
    float2 epv[GJ];

    // Stage 1: coalesced int2 index loads (clamped -> unconditional)
    #pragma unroll
    for (int j = 0; j < GJ; ++j) {
        int e = e_base + j * 256;
        e = (e < N_EDGES) ? e : (N_EDGES - 1);
        sdv[j] = sd[e];
    }
    // Stage 2: 2*GJ independent gathers in flight
    #pragma unroll
    for (int j = 0; j < GJ; ++j) {
        vsv[j] = vtab[sdv[j].x];
        vdv[j] = vtab[sdv[j].y];
    }
    // Stage 3: streaming loads
    #pragma unroll
    for (int j = 0; j < GJ; ++j) {
        int e = e_base + j * 256;
        e = (e < N_EDGES) ? e : (N_EDGES - 1);
        lgv[j] = logits[e];
        epv[j] = params[e];
    }
    // Stage 4: compute + masked stores + masked sums
    float s0 = 0.f, s1 = 0.f, q0 = 0.f, q1 = 0.f;
    #pragma unroll
    for (int j = 0; j < GJ; ++j) {
        const int  e  = e_base + j * 256;
        const bool ok = (e < N_EDGES);
        const float2 ep = epv[j];
        const float p   = 1.0f / (1.0f + __expf(-lgv[j]));
        const float cur = fabsf(vsv[j] - vdv[j]) / (ep.x + ep.y + EPS_F) * p;
        if (ok) {
            cur_out[e] = cur;
            s0 += ep.x; s1 += ep.y;
            q0 += ep.x * ep.x; q1 += ep.y * ep.y;
        }
    }

    s0 = wave_reduce(s0);
    s1 = wave_reduce(s1);
    q0 = wave_reduce(q0);
    q1 = wave_reduce(q1);
    if ((threadIdx.x & 63) == 0) {
        fadd_agent(acc + 0, s0);
        fadd_agent(acc + 1, s1);
        fadd_agent(acc + 2, q0);
        fadd_agent(acc + 3, q1);
    }
}

// ---------------- pass 3: LDS-binned scatter; chunk-per-XCD mapping ----------------
__global__ __launch_bounds__(256) void scatter_kernel(float* __restrict__ ws)
{
    __shared__ float bins[SLICE_N];   // 50 KB

    // All 512 blocks are co-resident (2/CU). blockIdx%8 selects the XCD, so
    // c = blockIdx&63 puts all 8 slice-blocks of chunk c on ONE XCD: the 8x
    // chunk re-scan is served by that XCD's L2 instead of L3.
    const int c  = blockIdx.x & (NCHUNK - 1);
    const int s  = blockIdx.x >> 6;
    const int lo = s * SLICE_N;

    for (int j = threadIdx.x; j < SLICE_N; j += 256) bins[j] = 0.f;
    __syncthreads();

    const int2*  sd  = (const int2*)(ws + SD_OFF);
    const float* cur = ws + CUR_OFF;

    const int e0 = c * CHUNK_E;
    const int e1 = e0 + CHUNK_E;

    for (int base = e0 + threadIdx.x; base < e1; base += 1024) {
        int2  sd4[4];
        float v4[4];
        #pragma unroll
        for (int k = 0; k < 4; ++k) {
            int e = base + k * 256;
            e = (e < e1) ? e : (e1 - 1);   // clamp: loads stay unconditional
            sd4[k] = sd[e];
            v4[k]  = cur[e];
        }
        #pragma unroll
        for (int k = 0; k < 4; ++k) {
            if (base + k * 256 < e1) {
                const unsigned ds = (unsigned)(sd4[k].y - lo);
                const unsigned ss = (unsigned)(sd4[k].x - lo);
                if (ds < SLICE_N) atomicAdd(&bins[ds],  v4[k]);
                if (ss < SLICE_N) atomicAdd(&bins[ss], -v4[k]);
            }
        }
    }
    __syncthreads();

    float* p = ws + PART_OFF + (size_t)c * N_NODES + lo;
    for (int j = threadIdx.x; j < SLICE_N; j += 256) p[j] = bins[j];
}

// ---------------- pass 4: merge partials, sum of squares ----------------
__global__ __launch_bounds__(256) void kcl_kernel(float* __restrict__ ws)
{
    const int i = blockIdx.x * blockDim.x + threadIdx.x;
    float acc = 0.f;
    if (i < N_NODES) {
        const float* p = ws + PART_OFF + i;
        float s = 0.f;
        #pragma unroll 8
        for (int c = 0; c < NCHUNK; ++c) s += p[(size_t)c * N_NODES];
        acc = s * s;
    }
    acc = wave_reduce(acc);
    if ((threadIdx.x & 63) == 0) fadd_agent(ws + 5, acc);
}

__global__ void final_kernel(const float* __restrict__ ws, float* __restrict__ out)
{
    const float s0 = ws[1], s1 = ws[2], q0 = ws[3], q1 = ws[4], k = ws[5];
    const float n  = (float)N_EDGES;
    const float var0 = (q0 - s0 * s0 / n) / (n - 1.0f);
    const float var1 = (q1 - s1 * s1 / n) / (n - 1.0f);
    out[0] = k / (float)N_NODES + 0.5f * (var0 + var1);
}

// ---------------- fallback (ws too small): agent-atomic scatter ----------------
#define FB_NODE_OFF 64
__global__ __launch_bounds__(256) void edge_kernel_fb(
    const float*  __restrict__ nf,
    const void*   __restrict__ eidx,
    const float*  __restrict__ logits,
    const float2* __restrict__ params,
    float*        __restrict__ ws)
{
    const int*       i32 = (const int*)eidx;
    const long long* i64 = (const long long*)eidx;
    int any = 0;
    #pragma unroll
    for (int k = 1; k < 32; k += 2) any |= i32[k];
    const bool is32 = (any != 0);

    float* node_sum = ws + FB_NODE_OFF;
    float* acc      = ws + 1;

    float s0 = 0.f, s1 = 0.f, q0 = 0.f, q1 = 0.f;
    const int tid    = blockIdx.x * blockDim.x + threadIdx.x;
    const int stride = gridDim.x * blockDim.x;
    for (int i = tid; i < N_EDGES; i += stride) {
        int src, dst;
        if (is32) { src = i32[i]; dst = i32[N_EDGES + i]; }
        else      { src = (int)i64[i]; dst = (int)i64[N_EDGES + i]; }
        const float2 ep = params[i];
        const float  p  = 1.0f / (1.0f + __expf(-logits[i]));
        const float cur = fabsf(nf[src * 4] - nf[dst * 4]) / (ep.x + ep.y + EPS_F) * p;
        fadd_agent(node_sum + dst,  cur);
        fadd_agent(node_sum + src, -cur);
        s0 += ep.x; s1 += ep.y; q0 += ep.x * ep.x; q1 += ep.y * ep.y;
    }
    s0 = wave_reduce(s0); s1 = wave_reduce(s1);
    q0 = wave_reduce(q0); q1 = wave_reduce(q1);
    if ((threadIdx.x & 63) == 0) {
        fadd_agent(acc + 0, s0); fadd_agent(acc + 1, s1);
        fadd_agent(acc + 2, q0); fadd_agent(acc + 3, q1);
    }
}

__global__ __launch_bounds__(256) void kcl_kernel_fb(float* __restrict__ ws)
{
    const float* node_sum = ws + FB_NODE_OFF;
    float acc = 0.f;
    const int tid    = blockIdx.x * blockDim.x + threadIdx.x;
    const int stride = gridDim.x * blockDim.x;
    for (int i = tid; i < N_NODES; i += stride) {
        const float v = node_sum[i];
        acc += v * v;
    }
    acc = wave_reduce(acc);
    if ((threadIdx.x & 63) == 0) fadd_agent(ws + 5, acc);
}

extern "C" void kernel_launch(void* const* d_in, const int* in_sizes, int n_in,
                              void* d_out, int out_size, void* d_ws, size_t ws_size,
                              hipStream_t stream) {
    const float*  nf     = (const float*)d_in[0];
    const void*   eidx   = d_in[1];
    const float*  logits = (const float*)d_in[2];
    const float2* params = (const float2*)d_in[3];
    float* ws  = (float*)d_ws;
    float* out = (float*)d_out;

    const size_t need = (size_t)WS_FLOATS * sizeof(float);   // ~64.4 MB

    if (ws_size >= need) {
        hipMemsetAsync(d_ws, 0, 256, stream);
        packv_kernel<<<(N_NODES + 255) / 256, 256, 0, stream>>>(nf, ws);
        repack_kernel<<<(N_EDGES + R_EPB - 1) / R_EPB, 256, 0, stream>>>(eidx, ws);
        gather_kernel<<<(N_EDGES + G_EPB - 1) / G_EPB, 256, 0, stream>>>(logits, params, ws);
        scatter_kernel<<<NCHUNK * NSLICE, 256, 0, stream>>>(ws);
        kcl_kernel<<<(N_NODES + 255) / 256, 256, 0, stream>>>(ws);
    } else {
        hipMemsetAsync(d_ws, 0, 256 + (size_t)N_NODES * sizeof(float), stream);
        edge_kernel_fb<<<2048, 256, 0, stream>>>(nf, eidx, logits, params, ws);
        kcl_kernel_fb<<<200, 256, 0, stream>>>(ws);
    }

    final_kernel<<<1, 1, 0, stream>>>(ws, out);
}